// Round 10
// baseline (253.643 us; speedup 1.0000x reference)
//
#include <hip/hip_runtime.h>
#include <hip/hip_bf16.h>

// EdgeDetourHead: B=2, N=512, E=128, H=256
// h1 = relu( [ |h_i-h_j| | h_j | e_ij ] @ [W1c; W1b; w1d] + PA[i] )  (PA = h_i@W1a + b1, fp32)
// h2 = relu( h1@W2 + b2 ) ;  p = h2@W3 + b3 ;  out = 0.5*(p+p^T), zero diag
//
// R10 = R9 (persistent R6) with the anti-lockstep stagger keyed on the RIGHT
// discriminator: with 512 WGs on 256 CUs, co-resident pairs are (x, x+256),
// so (blockIdx >> 8) & 1 separates them (R9's wave-slot parity could not —
// it delayed every WG uniformly). Odd-half WGs sleep ~32K cyc once, putting
// their MFMA phases over the partner's VALU/LDS phases (sum -> partial max).

#define BN 512
#define EE 128
#define HH 256

typedef __attribute__((ext_vector_type(8)))  short short8;
typedef __attribute__((ext_vector_type(4)))  short short4v;
typedef __attribute__((ext_vector_type(16))) float f32x16;
typedef __attribute__((ext_vector_type(4)))  float f32x4;

static __device__ __forceinline__ unsigned short f2bf(float f) {
    __bf16 h = (__bf16)f;
    return __builtin_bit_cast(unsigned short, h);
}
static __device__ __forceinline__ f32x16 zero16() {
    f32x16 v;
    #pragma unroll
    for (int i = 0; i < 16; ++i) v[i] = 0.f;
    return v;
}
#define MFMA(a, b, c) __builtin_amdgcn_mfma_f32_32x32x16_bf16((a), (b), (c), 0, 0, 0)

// ---------------- kernel 0: prep = weight pack (blocks 0..255) + PA (256..1279) ----
__global__ void prep(const float* __restrict__ node, const float* __restrict__ W1,
                     const float* __restrict__ W2, const float* __restrict__ b1,
                     float* __restrict__ PA,
                     unsigned short* __restrict__ w1c_p, unsigned short* __restrict__ w1b_p,
                     unsigned short* __restrict__ w2_p,  unsigned short* __restrict__ w1d_f) {
    int blk = blockIdx.x;
    if (blk < 256) {
        int idx = blk * 256 + threadIdx.x;             // 0..65535
        {                                              // W2^T A-frags: kb 0..15
            int t = idx & 7, l = (idx >> 3) & 63, mt = (idx >> 9) & 7, kb = idx >> 12;
            int k = kb * 16 + (l >> 5) * 8 + t, m = mt * 32 + (l & 31);
            w2_p[idx] = f2bf(W2[k * HH + m]);
            if (idx < 32768) {                         // W1c^T, W1b^T: kb 0..7
                w1c_p[idx] = f2bf(W1[(2 * EE + k) * HH + m]);
                w1b_p[idx] = f2bf(W1[(EE + k) * HH + m]);
            }
        }
        if (idx < 4096) {                              // w1d^T rank-1 A-frags (k=0 col)
            int t = idx & 7, l = (idx >> 3) & 63, mt = idx >> 9;
            int m = mt * 32 + (l & 31);
            bool nz = (t == 0 && l < 32);
            w1d_f[idx] = nz ? f2bf(W1[(3 * EE) * HH + m]) : (unsigned short)0;
        }
    } else {
        int bi = blk - 256;                            // 0..1023
        int h = threadIdx.x;
        const float* nd = node + (size_t)bi * EE;
        float sa = b1[h];
        #pragma unroll 8
        for (int e = 0; e < EE; ++e) sa += nd[e] * W1[e * HH + h];
        PA[bi * HH + h] = sa;
    }
}

// ---------------- kernel 1: persistent fused main (8 tiles per WG) ----------------
__global__ __launch_bounds__(256, 2) void edge_main(
    const float* __restrict__ node, const float* __restrict__ euclid,
    const float* __restrict__ W3, const float* __restrict__ b3,
    const float* __restrict__ b2v, const float* __restrict__ PA,
    const unsigned short* __restrict__ w1c_p, const unsigned short* __restrict__ w1b_p,
    const unsigned short* __restrict__ w2_p,  const unsigned short* __restrict__ w1d_f,
    float* __restrict__ out)
{
    __shared__ __align__(16) unsigned short lds_buf[2 * 128 * 136];
    __shared__ float pp[512];

    const int id = blockIdx.x;

    // ---- anti-lockstep stagger: second dispatch sweep (id >= 256) sleeps ----
    // ~32K cycles = ~half the per-tile period, WG-wide, once.
    if ((id >> 8) & 1) {
        __builtin_amdgcn_s_sleep(127);
        __builtin_amdgcn_s_sleep(127);
        __builtin_amdgcn_s_sleep(127);
        __builtin_amdgcn_s_sleep(127);
    }

    const int jt = id & 3, b = (id >> 2) & 1, ig = id >> 3;
    const int jbase = jt * 128, i0 = (ig & 63) * 8;
    const int tid = threadIdx.x, wave = tid >> 6, lane = tid & 63;
    const int m0 = lane & 31, q = lane >> 5;
    const int brow = tid >> 1, bhalf = tid & 1;

    unsigned short* ldsD  = lds_buf;
    unsigned short* ldsHJ = lds_buf + 128 * 136;
    unsigned short* ldsH1 = lds_buf;                   // overwrites D+hj after K1

    const float b3v = b3[0];
    const short8 aw0 = ((const short8*)w1d_f)[(wave * 2 + 0) * 64 + lane];
    const short8 aw1 = ((const short8*)w1d_f)[(wave * 2 + 1) * 64 + lane];

    #pragma unroll 1
    for (int tt = 0; tt < 8; ++tt) {
        const int i = i0 + tt;
        // Opaque zero offset: blocks cross-tile LICM of invariant streams
        // (the R4/R7 spill mode); SGPR-cheap reload per tile instead.
        size_t z = 0;
        asm volatile("" : "+s"(z));
        const short8* wcT = (const short8*)w1c_p + z;
        const short8* wbT = (const short8*)w1b_p + z;
        const short8* w2T = (const short8*)w2_p + z;
        const f32x4*  njT = (const f32x4*)(node + ((size_t)b * BN + jbase + brow) * EE) + z;
        const float*  b2T = b2v + z;
        const float*  w3T = W3 + z;

        // ---- phase 1: build D=|h_i-h_j| and hj (bf16) row-major, stride 136 ----
        {
            const f32x4* hv = (const f32x4*)(node + ((size_t)b * BN + i) * EE);
            #pragma unroll
            for (int g = 0; g < 8; ++g) {
                int c0 = bhalf * 16 + g * 2;           // f32x4 index
                f32x4 a0 = njT[c0], a1 = njT[c0 + 1];
                f32x4 h0 = hv[c0],  h1v = hv[c0 + 1];
                short8 pd, ph;
                #pragma unroll
                for (int u = 0; u < 4; ++u) {
                    pd[u]     = (short)f2bf(fabsf(a0[u] - h0[u]));
                    pd[4 + u] = (short)f2bf(fabsf(a1[u] - h1v[u]));
                    ph[u]     = (short)f2bf(a0[u]);
                    ph[4 + u] = (short)f2bf(a1[u]);
                }
                int off = brow * 136 + bhalf * 64 + g * 8;
                *(short8*)&ldsD[off]  = pd;
                *(short8*)&ldsHJ[off] = ph;
            }
        }
        __syncthreads();

        // ---- layer 1 (transposed): C1^T = W1c^T@D^T + W1b^T@hj^T + w1d^T@e^T ----
        f32x16 acc[2][4];
        #pragma unroll
        for (int mt = 0; mt < 2; ++mt)
            #pragma unroll
            for (int nt = 0; nt < 4; ++nt) acc[mt][nt] = zero16();
        {
            const int mtg = wave * 2;
            #pragma unroll
            for (int kb = 0; kb < 8; ++kb) {
                short8 ac0 = wcT[(kb * 8 + mtg + 0) * 64 + lane];
                short8 ac1 = wcT[(kb * 8 + mtg + 1) * 64 + lane];
                short8 ab0 = wbT[(kb * 8 + mtg + 0) * 64 + lane];
                short8 ab1 = wbT[(kb * 8 + mtg + 1) * 64 + lane];
                #pragma unroll
                for (int nt = 0; nt < 4; ++nt) {
                    int off = (nt * 32 + m0) * 136 + kb * 16 + q * 8;
                    short8 bD  = *(const short8*)&ldsD[off];
                    short8 bHJ = *(const short8*)&ldsHJ[off];
                    acc[0][nt] = MFMA(ac0, bD, acc[0][nt]);
                    acc[1][nt] = MFMA(ac1, bD, acc[1][nt]);
                    acc[0][nt] = MFMA(ab0, bHJ, acc[0][nt]);
                    acc[1][nt] = MFMA(ab1, bHJ, acc[1][nt]);
                }
            }
            // rank-1 e*w1d
            const float* erow = euclid + ((size_t)b * BN + i) * BN + jbase;
            #pragma unroll
            for (int nt = 0; nt < 4; ++nt) {
                short8 be;
                #pragma unroll
                for (int u = 0; u < 8; ++u) be[u] = 0;
                if (lane < 32) be[0] = (short)f2bf(erow[nt * 32 + m0]);
                acc[0][nt] = MFMA(aw0, be, acc[0][nt]);
                acc[1][nt] = MFMA(aw1, be, acc[1][nt]);
            }
        }
        __syncthreads();   // D + hj dead

        // ---- epi1: h1[pair][feat] = relu(C1^T + PA[feat]) -> stride 264, b64 ----
        {
            const float* paB = PA + ((size_t)b * BN + i) * HH;
            #pragma unroll
            for (int mt = 0; mt < 2; ++mt) {
                #pragma unroll
                for (int rg = 0; rg < 4; ++rg) {
                    int f0 = wave * 64 + mt * 32 + rg * 8 + 4 * q;
                    f32x4 pav = *(const f32x4*)&paB[f0];
                    #pragma unroll
                    for (int nt = 0; nt < 4; ++nt) {
                        short4v w;
                        #pragma unroll
                        for (int u = 0; u < 4; ++u) {
                            float v = acc[mt][nt][rg * 4 + u] + pav[u];
                            v = v > 0.f ? v : 0.f;
                            w[u] = (short)f2bf(v);
                        }
                        *(short4v*)&ldsH1[(nt * 32 + m0) * 264 + f0] = w;
                    }
                }
            }
        }
        __syncthreads();

        // ---- layer 2 (transposed): C2^T = W2^T @ h1^T ----
        f32x16 c2[2][4];
        #pragma unroll
        for (int mt = 0; mt < 2; ++mt)
            #pragma unroll
            for (int nt = 0; nt < 4; ++nt) c2[mt][nt] = zero16();
        {
            const int mtg = wave * 2;
            #pragma unroll
            for (int kb = 0; kb < 16; ++kb) {
                short8 a0 = w2T[(kb * 8 + mtg + 0) * 64 + lane];
                short8 a1 = w2T[(kb * 8 + mtg + 1) * 64 + lane];
                #pragma unroll
                for (int nt = 0; nt < 4; ++nt) {
                    short8 bh = *(const short8*)&ldsH1[(nt * 32 + m0) * 264 + kb * 16 + q * 8];
                    c2[0][nt] = MFMA(a0, bh, c2[0][nt]);
                    c2[1][nt] = MFMA(a1, bh, c2[1][nt]);
                }
            }
        }

        // ---- layer 3 in registers: s[nt] = sum_f relu(c2 + b2[f]) * W3[f] ----
        {
            float s[4] = {0.f, 0.f, 0.f, 0.f};
            #pragma unroll
            for (int mt = 0; mt < 2; ++mt) {
                #pragma unroll
                for (int rg = 0; rg < 4; ++rg) {
                    int f0 = wave * 64 + mt * 32 + rg * 8 + 4 * q;
                    f32x4 bb = *(const f32x4*)&b2T[f0];
                    f32x4 ww = *(const f32x4*)&w3T[f0];
                    #pragma unroll
                    for (int u = 0; u < 4; ++u) {
                        #pragma unroll
                        for (int nt = 0; nt < 4; ++nt) {
                            float h2 = c2[mt][nt][rg * 4 + u] + bb[u];
                            h2 = h2 > 0.f ? h2 : 0.f;
                            s[nt] += h2 * ww[u];
                        }
                    }
                }
            }
            #pragma unroll
            for (int nt = 0; nt < 4; ++nt)
                s[nt] += __shfl_xor(s[nt], 32, 64);    // fold q-halves (same pair)
            if (lane < 32) {
                #pragma unroll
                for (int nt = 0; nt < 4; ++nt)
                    pp[wave * 128 + nt * 32 + lane] = s[nt];
            }
        }
        __syncthreads();
        if (tid < 128) {
            float v = pp[tid] + pp[128 + tid] + pp[256 + tid] + pp[384 + tid] + b3v;
            out[((size_t)b * BN + i) * BN + jbase + tid] = v;
        }
        // next iteration's build writes lds_buf only after this sync; pp is
        // read here and rewritten 4 syncs later -> safe.
    }
}

// ---------------- kernel 2: in-place symmetrize + zero diagonal ----------------
__global__ void symmetrize(float* __restrict__ out) {
    int b = blockIdx.z, ti = blockIdx.y, tj = blockIdx.x;
    if (tj < ti) return;
    int i = ti * 32 + threadIdx.y, j = tj * 32 + threadIdx.x;
    float* p = out + (size_t)b * BN * BN;
    if (i == j) { p[(size_t)i * BN + j] = 0.f; return; }
    if (j < i) return;
    float a = p[(size_t)i * BN + j];
    float c = p[(size_t)j * BN + i];
    float v = 0.5f * (a + c);
    p[(size_t)i * BN + j] = v;
    p[(size_t)j * BN + i] = v;
}

extern "C" void kernel_launch(void* const* d_in, const int* in_sizes, int n_in,
                              void* d_out, int out_size, void* d_ws, size_t ws_size,
                              hipStream_t stream) {
    const float* node   = (const float*)d_in[0];
    const float* euclid = (const float*)d_in[2];
    const float* W1     = (const float*)d_in[3];
    const float* b1     = (const float*)d_in[4];
    const float* W2     = (const float*)d_in[5];
    const float* b2     = (const float*)d_in[6];
    const float* W3     = (const float*)d_in[7];
    const float* b3     = (const float*)d_in[8];
    float* out = (float*)d_out;

    char* ws = (char*)d_ws;
    float*          PA    = (float*)ws;                                   // 1 MB
    unsigned short* w1c_p = (unsigned short*)(ws + (1u << 20));           // 64 KB
    unsigned short* w1b_p = (unsigned short*)(ws + (1u << 20) + 65536);   // 64 KB
    unsigned short* w2_p  = (unsigned short*)(ws + (1u << 20) + 131072);  // 128 KB
    unsigned short* w1d_f = (unsigned short*)(ws + (1u << 20) + 262144);  // 8 KB

    prep<<<1280, 256, 0, stream>>>(node, W1, W2, b1, PA, w1c_p, w1b_p, w2_p, w1d_f);
    edge_main<<<512, 256, 0, stream>>>(
        node, euclid, W3, b3, b2, PA, w1c_p, w1b_p, w2_p, w1d_f, out);
    symmetrize<<<dim3(BN / 32, BN / 32, 2), dim3(32, 32), 0, stream>>>(out);
}

// Round 11
// 244.951 us; speedup vs baseline: 1.0355x; 1.0355x over previous
//
#include <hip/hip_runtime.h>
#include <hip/hip_bf16.h>

// EdgeDetourHead: B=2, N=512, E=128, H=256
// h1 = relu( [ |h_i-h_j| | h_j | e_ij ] @ [W1c; W1b; w1d] + PA[i] )  (PA = h_i@W1a + b1, fp32)
// h2 = relu( h1@W2 + b2 ) ;  p = h2@W3 + b3 ;  out = 0.5*(p+p^T), zero diag
//
// R11 = R6 transposed dataflow at HALF tile (64 pairs/WG) for occupancy:
// LDS 35.8 KB/WG -> 4 WG/CU, 16 waves/CU (was 71.7 KB -> 2 WG/CU, 20% occ).
// Diagnosis: no pipe saturated (MFMA 30 / VALU 21 / LDS 27 / HBM 0.5) =>
// latency-bound; double the resident waves. Weight VMEM doubles per pair
// (~1 GB L2 aggregate, ~30us, overlappable) - accepted trade.
// Wave = 64 feats x 64 pairs: acc[2][2] = 64 VGPR, launch_bounds(256,4).

#define BN 512
#define EE 128
#define HH 256

typedef __attribute__((ext_vector_type(8)))  short short8;
typedef __attribute__((ext_vector_type(4)))  short short4v;
typedef __attribute__((ext_vector_type(16))) float f32x16;
typedef __attribute__((ext_vector_type(4)))  float f32x4;

static __device__ __forceinline__ unsigned short f2bf(float f) {
    __bf16 h = (__bf16)f;
    return __builtin_bit_cast(unsigned short, h);
}
static __device__ __forceinline__ f32x16 zero16() {
    f32x16 v;
    #pragma unroll
    for (int i = 0; i < 16; ++i) v[i] = 0.f;
    return v;
}
#define MFMA(a, b, c) __builtin_amdgcn_mfma_f32_32x32x16_bf16((a), (b), (c), 0, 0, 0)

// ---------------- kernel 0: prep = weight pack (blocks 0..255) + PA (256..1279) ----
// Packed frag idx = ((kb*8 + mtile)*64 + l)*8 + t ; value W[kb*16+(l>>5)*8+t][mtile*32+(l&31)]
// == A-frag of W^T for the transposed kernel.
__global__ void prep(const float* __restrict__ node, const float* __restrict__ W1,
                     const float* __restrict__ W2, const float* __restrict__ b1,
                     float* __restrict__ PA,
                     unsigned short* __restrict__ w1c_p, unsigned short* __restrict__ w1b_p,
                     unsigned short* __restrict__ w2_p,  unsigned short* __restrict__ w1d_f) {
    int blk = blockIdx.x;
    if (blk < 256) {
        int idx = blk * 256 + threadIdx.x;             // 0..65535
        {                                              // W2^T A-frags: kb 0..15
            int t = idx & 7, l = (idx >> 3) & 63, mt = (idx >> 9) & 7, kb = idx >> 12;
            int k = kb * 16 + (l >> 5) * 8 + t, m = mt * 32 + (l & 31);
            w2_p[idx] = f2bf(W2[k * HH + m]);
            if (idx < 32768) {                         // W1c^T, W1b^T: kb 0..7
                w1c_p[idx] = f2bf(W1[(2 * EE + k) * HH + m]);
                w1b_p[idx] = f2bf(W1[(EE + k) * HH + m]);
            }
        }
        if (idx < 4096) {                              // w1d^T rank-1 A-frags (k=0 col)
            int t = idx & 7, l = (idx >> 3) & 63, mt = idx >> 9;
            int m = mt * 32 + (l & 31);
            bool nz = (t == 0 && l < 32);
            w1d_f[idx] = nz ? f2bf(W1[(3 * EE) * HH + m]) : (unsigned short)0;
        }
    } else {
        int bi = blk - 256;                            // 0..1023
        int h = threadIdx.x;
        const float* nd = node + (size_t)bi * EE;
        float sa = b1[h];
        #pragma unroll 8
        for (int e = 0; e < EE; ++e) sa += nd[e] * W1[e * HH + h];
        PA[bi * HH + h] = sa;
    }
}

// ---------------- kernel 1: fused main, one 64-pair x 256-feat tile per WG ----------------
// Wave w owns feats [64w, 64w+64) (m-tiles 2w, 2w+1) x both 32-pair n-tiles.
__global__ __launch_bounds__(256, 4) void edge_main(
    const float* __restrict__ node, const float* __restrict__ euclid,
    const float* __restrict__ W3, const float* __restrict__ b3,
    const float* __restrict__ b2v, const float* __restrict__ PA,
    const unsigned short* __restrict__ w1c_p, const unsigned short* __restrict__ w1b_p,
    const unsigned short* __restrict__ w2_p,  const unsigned short* __restrict__ w1d_f,
    float* __restrict__ out)
{
    // D [64][136] + HJ [64][136] = 34816 B; h1 [64][264] (33792 B) overlays both.
    __shared__ __align__(16) unsigned short lds_buf[2 * 64 * 136];
    __shared__ float pp[256];                          // total 35840 B -> 4 WG/CU

    const int jt = blockIdx.x, i = blockIdx.y, b = blockIdx.z;
    const int jbase = jt * 64;
    const int tid = threadIdx.x, wave = tid >> 6, lane = tid & 63;
    const int m0 = lane & 31, q = lane >> 5;
    const int brow = tid >> 2, bq4 = tid & 3;          // build: 4 thr/row, 32 cols each

    unsigned short* ldsD  = lds_buf;
    unsigned short* ldsHJ = lds_buf + 64 * 136;
    unsigned short* ldsH1 = lds_buf;                   // stride 264 overlay after K1

    const float b3v = b3[0];
    const short8 aw0 = ((const short8*)w1d_f)[(wave * 2 + 0) * 64 + lane];
    const short8 aw1 = ((const short8*)w1d_f)[(wave * 2 + 1) * 64 + lane];

    // ---- phase 1: build D=|h_i-h_j| and hj (bf16) row-major [pair][e], stride 136 ----
    {
        const f32x4* nj = (const f32x4*)(node + ((size_t)b * BN + jbase + brow) * EE);
        const f32x4* hv = (const f32x4*)(node + ((size_t)b * BN + i) * EE);
        #pragma unroll
        for (int g = 0; g < 4; ++g) {
            int c0 = bq4 * 8 + g * 2;                  // f32x4 index
            f32x4 a0 = nj[c0], a1 = nj[c0 + 1];
            f32x4 h0 = hv[c0], h1v = hv[c0 + 1];
            short8 pd, ph;
            #pragma unroll
            for (int u = 0; u < 4; ++u) {
                pd[u]     = (short)f2bf(fabsf(a0[u] - h0[u]));
                pd[4 + u] = (short)f2bf(fabsf(a1[u] - h1v[u]));
                ph[u]     = (short)f2bf(a0[u]);
                ph[4 + u] = (short)f2bf(a1[u]);
            }
            int off = brow * 136 + bq4 * 32 + g * 8;
            *(short8*)&ldsD[off]  = pd;
            *(short8*)&ldsHJ[off] = ph;
        }
    }
    __syncthreads();

    // ---- layer 1 (transposed): C1^T = W1c^T@D^T + W1b^T@hj^T + w1d^T@e^T ----
    f32x16 acc[2][2];
    acc[0][0] = zero16(); acc[0][1] = zero16();
    acc[1][0] = zero16(); acc[1][1] = zero16();
    {
        const short8* wc = (const short8*)w1c_p;
        const short8* wb = (const short8*)w1b_p;
        const int mtg = wave * 2;
        #pragma unroll
        for (int kb = 0; kb < 8; ++kb) {
            short8 ac0 = wc[(kb * 8 + mtg + 0) * 64 + lane];
            short8 ac1 = wc[(kb * 8 + mtg + 1) * 64 + lane];
            short8 ab0 = wb[(kb * 8 + mtg + 0) * 64 + lane];
            short8 ab1 = wb[(kb * 8 + mtg + 1) * 64 + lane];
            #pragma unroll
            for (int nt = 0; nt < 2; ++nt) {
                int off = (nt * 32 + m0) * 136 + kb * 16 + q * 8;
                short8 bD  = *(const short8*)&ldsD[off];
                short8 bHJ = *(const short8*)&ldsHJ[off];
                acc[0][nt] = MFMA(ac0, bD, acc[0][nt]);
                acc[1][nt] = MFMA(ac1, bD, acc[1][nt]);
                acc[0][nt] = MFMA(ab0, bHJ, acc[0][nt]);
                acc[1][nt] = MFMA(ab1, bHJ, acc[1][nt]);
            }
        }
        // rank-1 e*w1d
        const float* erow = euclid + ((size_t)b * BN + i) * BN + jbase;
        #pragma unroll
        for (int nt = 0; nt < 2; ++nt) {
            short8 be;
            #pragma unroll
            for (int u = 0; u < 8; ++u) be[u] = 0;
            if (lane < 32) be[0] = (short)f2bf(erow[nt * 32 + m0]);
            acc[0][nt] = MFMA(aw0, be, acc[0][nt]);
            acc[1][nt] = MFMA(aw1, be, acc[1][nt]);
        }
    }
    __syncthreads();   // D + hj dead

    // ---- epi1: h1[pair][feat] = relu(C1^T + PA[feat]) -> stride 264, b64 writes ----
    {
        const float* paB = PA + ((size_t)b * BN + i) * HH;
        #pragma unroll
        for (int mt = 0; mt < 2; ++mt) {
            #pragma unroll
            for (int rg = 0; rg < 4; ++rg) {
                int f0 = wave * 64 + mt * 32 + rg * 8 + 4 * q;
                f32x4 pav = *(const f32x4*)&paB[f0];
                #pragma unroll
                for (int nt = 0; nt < 2; ++nt) {
                    short4v w;
                    #pragma unroll
                    for (int u = 0; u < 4; ++u) {
                        float v = acc[mt][nt][rg * 4 + u] + pav[u];
                        v = v > 0.f ? v : 0.f;
                        w[u] = (short)f2bf(v);
                    }
                    *(short4v*)&ldsH1[(nt * 32 + m0) * 264 + f0] = w;
                }
            }
        }
    }
    __syncthreads();

    // ---- layer 2 (transposed): C2^T = W2^T @ h1^T ----
    f32x16 c2[2][2];
    c2[0][0] = zero16(); c2[0][1] = zero16();
    c2[1][0] = zero16(); c2[1][1] = zero16();
    {
        const short8* w2f = (const short8*)w2_p;
        const int mtg = wave * 2;
        #pragma unroll
        for (int kb = 0; kb < 16; ++kb) {
            short8 a0 = w2f[(kb * 8 + mtg + 0) * 64 + lane];
            short8 a1 = w2f[(kb * 8 + mtg + 1) * 64 + lane];
            #pragma unroll
            for (int nt = 0; nt < 2; ++nt) {
                short8 bh = *(const short8*)&ldsH1[(nt * 32 + m0) * 264 + kb * 16 + q * 8];
                c2[0][nt] = MFMA(a0, bh, c2[0][nt]);
                c2[1][nt] = MFMA(a1, bh, c2[1][nt]);
            }
        }
    }

    // ---- layer 3 in registers: s[nt] = sum_f relu(c2 + b2[f]) * W3[f] ----
    {
        float s[2] = {0.f, 0.f};
        #pragma unroll
        for (int mt = 0; mt < 2; ++mt) {
            #pragma unroll
            for (int rg = 0; rg < 4; ++rg) {
                int f0 = wave * 64 + mt * 32 + rg * 8 + 4 * q;
                f32x4 bb = *(const f32x4*)&b2v[f0];
                f32x4 ww = *(const f32x4*)&W3[f0];
                #pragma unroll
                for (int u = 0; u < 4; ++u) {
                    #pragma unroll
                    for (int nt = 0; nt < 2; ++nt) {
                        float h2 = c2[mt][nt][rg * 4 + u] + bb[u];
                        h2 = h2 > 0.f ? h2 : 0.f;
                        s[nt] += h2 * ww[u];
                    }
                }
            }
        }
        #pragma unroll
        for (int nt = 0; nt < 2; ++nt)
            s[nt] += __shfl_xor(s[nt], 32, 64);        // fold q-halves (same pair)
        if (lane < 32) {
            pp[wave * 64 + lane]      = s[0];
            pp[wave * 64 + 32 + lane] = s[1];
        }
    }
    __syncthreads();
    if (tid < 64) {
        float v = pp[tid] + pp[64 + tid] + pp[128 + tid] + pp[192 + tid] + b3v;
        out[((size_t)b * BN + i) * BN + jbase + tid] = v;
    }
}

// ---------------- kernel 2: in-place symmetrize + zero diagonal ----------------
__global__ void symmetrize(float* __restrict__ out) {
    int b = blockIdx.z, ti = blockIdx.y, tj = blockIdx.x;
    if (tj < ti) return;
    int i = ti * 32 + threadIdx.y, j = tj * 32 + threadIdx.x;
    float* p = out + (size_t)b * BN * BN;
    if (i == j) { p[(size_t)i * BN + j] = 0.f; return; }
    if (j < i) return;
    float a = p[(size_t)i * BN + j];
    float c = p[(size_t)j * BN + i];
    float v = 0.5f * (a + c);
    p[(size_t)i * BN + j] = v;
    p[(size_t)j * BN + i] = v;
}

extern "C" void kernel_launch(void* const* d_in, const int* in_sizes, int n_in,
                              void* d_out, int out_size, void* d_ws, size_t ws_size,
                              hipStream_t stream) {
    const float* node   = (const float*)d_in[0];
    const float* euclid = (const float*)d_in[2];
    const float* W1     = (const float*)d_in[3];
    const float* b1     = (const float*)d_in[4];
    const float* W2     = (const float*)d_in[5];
    const float* b2     = (const float*)d_in[6];
    const float* W3     = (const float*)d_in[7];
    const float* b3     = (const float*)d_in[8];
    float* out = (float*)d_out;

    char* ws = (char*)d_ws;
    float*          PA    = (float*)ws;                                   // 1 MB
    unsigned short* w1c_p = (unsigned short*)(ws + (1u << 20));           // 64 KB
    unsigned short* w1b_p = (unsigned short*)(ws + (1u << 20) + 65536);   // 64 KB
    unsigned short* w2_p  = (unsigned short*)(ws + (1u << 20) + 131072);  // 128 KB
    unsigned short* w1d_f = (unsigned short*)(ws + (1u << 20) + 262144);  // 8 KB

    prep<<<1280, 256, 0, stream>>>(node, W1, W2, b1, PA, w1c_p, w1b_p, w2_p, w1d_f);
    edge_main<<<dim3(BN / 64, BN, 2), 256, 0, stream>>>(
        node, euclid, W3, b3, b2, PA, w1c_p, w1b_p, w2_p, w1d_f, out);
    symmetrize<<<dim3(BN / 32, BN / 32, 2), dim3(32, 32), 0, stream>>>(out);
}